// Round 10
// baseline (405.311 us; speedup 1.0000x reference)
//
#include <hip/hip_runtime.h>
#include <hip/hip_bf16.h>

// 2-layer 4-direction MDLSTM, fused, one dispatch. B=256, Wd=2048, OUT=11.
// R17: R15 + __launch_bounds__(NTHR, 4). R15/R16 counters proved the
// compiler targeted 8 waves/EU at NTHR=1024 (VGPR capped 64) and SPILLED
// ~40 regs of weight state to scratch (FETCH 33->75.5 MB, WRITE
// 22.5->106.5 MB/dispatch). R16's amdgpu_waves_per_eu attribute was
// IGNORED (identical counters). The documented knob is the 2nd
// __launch_bounds__ arg = min waves per EU: 4 -> VGPR budget 512/4 = 128.
// R14's identical per-wave code needs 92 VGPR -> no spill, 36 headroom.
// Our 147 KB LDS limits to 1 WG/CU = 4 waves/EU anyway.
// R15 carried: 16 waves = 64 chains = 4 dirs x 16 chunks (CHUNK 128),
// WARM 40 (zero-init converges ~11 sigma below f16 quantum; 3.5x slack).
// R14 carried: unit-per-lane, 4 chains/wave, distribution = pure-VALU
// rotate-reduce (2 quad_perm + cvt_pkrtz put pair floor(u/2) in every
// lane; 7x dpp row_ror:2 rotates pairs through the 16-lane group;
// U-registers pre-permuted at setup, 8 slots, pairs 6/7 zero => exact;
// rotation direction resolved by runtime dpp probe). DS crossbar ops on
// the serial chain are banned (R12/R13: ~+900 cyc/step unhidden).
// ck0 runs wrapped/OOB-in-LDS garbage warm (benign) + state rezero at the
// main-loop boundary -> fully uniform control flow (proven R12-R15).
// f32 LDS atomic acc; f16-pair y strip; exp2-folded activations.

#define NOUT 11
#define WD 2048
#define NB 256
#define ROW 12
#define ACCN (WD * ROW)
#define YROW 6
#define YPAD 12
#define YBFN (WD * YROW + 2 * YPAD)

#define NTHR 1024
#define NCK 16      // chunks per direction
#define CHUNK 128   // WD / NCK
#define WARM 40     // uniform warm (ck0 wrapped+rezeroed); even

typedef float f2 __attribute__((ext_vector_type(2)));
typedef float f4 __attribute__((ext_vector_type(4)));
typedef unsigned int u32;
typedef u32 u32x2 __attribute__((ext_vector_type(2)));
typedef __fp16 h2 __attribute__((ext_vector_type(2)));

#define LOG2E 1.4426950408889634f

union UH { u32 u; h2 h; };
__device__ __forceinline__ u32 h2u(h2 v) { UH x; x.h = v; return x.u; }
__device__ __forceinline__ h2 u2h(u32 v) { UH x; x.u = v; return x.h; }

template <int CTRL>
__device__ __forceinline__ float dppf(float v) {
  return __int_as_float(__builtin_amdgcn_update_dpp(
      __float_as_int(v), __float_as_int(v), CTRL, 0xF, 0xF, false));
}
// row_ror:2 on a packed h2 (u32 bits); wraps within 16-lane rows.
__device__ __forceinline__ h2 rorh(h2 v) {
  return u2h((u32)__builtin_amdgcn_update_dpp(
      (int)h2u(v), (int)h2u(v), 0x122, 0xF, 0xF, false));
}
__device__ __forceinline__ float rcp_(float x) { return __builtin_amdgcn_rcpf(x); }
__device__ __forceinline__ float exp2_(float x) { return __builtin_amdgcn_exp2f(x); }
__device__ __forceinline__ float dot2(h2 a, h2 b, float c) {
  return __builtin_amdgcn_fdot2(a, b, c, false);
}

// DOACC: compile-time 0/1 (warm-up steps don't accumulate).
// In scope: hj, cpr, giI/F/O/A, ao, ad, UpI/F/O/A[8], wr, acc.
// __VA_ARGS__ = off-chain PREP (sets gnI/F/O/A).
#define STEP(DOACC, ...)                                                       \
  do {                                                                         \
    const float hEv = dppf<0xA0>(hj); /* quad_perm[0,0,2,2]: h_{2*(u>>1)} */   \
    const float hOd = dppf<0xF5>(hj); /* quad_perm[1,1,3,3]: h_{2*(u>>1)+1} */ \
    h2 rv = __builtin_amdgcn_cvt_pkrtz(hEv, hOd); /* pair p0 in every lane */  \
    __VA_ARGS__                                                                \
    float gI = dot2(rv, UpI[0], giI);                                          \
    float gF = dot2(rv, UpF[0], giF);                                          \
    float gO = dot2(rv, UpO[0], giO);                                          \
    float gA = dot2(rv, UpA[0], giA);                                          \
    _Pragma("unroll")                                                          \
    for (int s = 1; s < 8; ++s) {                                              \
      rv = rorh(rv);                                                           \
      gI = dot2(rv, UpI[s], gI);                                               \
      gF = dot2(rv, UpF[s], gF);                                               \
      gO = dot2(rv, UpO[s], gO);                                               \
      gA = dot2(rv, UpA[s], gA);                                               \
    }                                                                          \
    const float sI = rcp_(1.0f + exp2_(gI));                                   \
    const float sF = rcp_(1.0f + exp2_(gF));                                   \
    const float sO = rcp_(1.0f + exp2_(gO));                                   \
    const float sA = rcp_(1.0f + exp2_(gA));                                   \
    const float taS = fmaf(-4.0f * LOG2E, sA, 2.0f * LOG2E); /* -2L*tanh */    \
    cpr = fmaf(sF, cpr, sI * taS); /* cpr == -2*log2e*c */                     \
    const float r2t = rcp_(1.0f + exp2_(cpr)); /* sigma(2c) */                 \
    const float sO2 = sO + sO;                                                 \
    hj = fmaf(sO2, r2t, -sO); /* o * tanh(c) */                                \
    if (DOACC && wr) atomicAdd(&acc[ao], hj);                                  \
    ao += ad;                                                                  \
  } while (0)

__global__ __launch_bounds__(NTHR, 4) void mdlstm_fused(
    const float* __restrict__ x, const float* __restrict__ W0,
    const float* __restrict__ U0, const float* __restrict__ b0,
    const float* __restrict__ W1, const float* __restrict__ U1,
    const float* __restrict__ b1, float* __restrict__ out) {
  __shared__ __align__(16) float acc[ACCN];  // 96 KB
  __shared__ __align__(16) u32 ybf[YBFN];    // 48.1 KB (xw f32 | y f16-pairs)

  const int tid = threadIdx.x;
  const int b = blockIdx.x;
  float* xw = (float*)ybf;

  // ---- Phase A: height-sum x -> xw; zero acc ----
  {
    const f4* xb4 = (const f4*)(x + (size_t)b * 32 * WD);
    f4* xw4 = (f4*)xw;
    for (int w = tid; w < WD / 4; w += NTHR) {
      f4 s = xb4[w];
#pragma unroll
      for (int h = 1; h < 32; ++h) s += xb4[h * (WD / 4) + w];
      xw4[w] = s;
    }
    f4* a4 = (f4*)acc;
    const f4 z = {0.f, 0.f, 0.f, 0.f};
    for (int i = tid; i < ACCN / 4; i += NTHR) a4[i] = z;
  }
  __syncthreads();

  const int lane = tid & 63;
  const int wv = tid >> 6;          // 0..15
  const int grp = lane >> 4;        // group 0..3 = chain slot in wave
  const int u = lane & 15;          // unit 0..15 (11..15 dummy)
  const int chain = wv * 4 + grp;   // 0..63
  const int d = chain & 3;          // direction
  const int ck = chain >> 2;        // chunk 0..15
  const bool fwd = ((d & 1) == 0);
  const int base = ck * CHUNK;
  const bool real = (u <= 10);
  const bool wr = real;
  const bool ck0z = (ck == 0);      // wrapped warm -> rezero at boundary
  // gate cols: i:0-10 f:11-21 o:33-43 a:44-54; dummy -> col 54, scl 0
  const int colI = real ? u : 54;
  const int colF = real ? (11 + u) : 54;
  const int colO = real ? (33 + u) : 54;
  const int colA = real ? (44 + u) : 54;
  const float sclS = real ? -LOG2E : 0.f;          // i, f, o
  const float sclA = real ? (-2.f * LOG2E) : 0.f;  // a

  // Rotation-direction probe: does row_ror:2 read lane i+2 or i-2?
  const int li = lane & 15;
  const int pv =
      __builtin_amdgcn_update_dpp(0, li, 0x122, 0xF, 0xF, false);
  const bool rplus = (pv == ((li + 2) & 15));
  const int p0 = li >> 1;  // own pair index 0..7

  const int p0pos = fwd ? (base - WARM) : (WD - 1 - base + WARM);
  const int xd = fwd ? 1 : -1;
  const int ad = fwd ? ROW : -ROW;
  const int qd = fwd ? 3 : -3;

  // Rotated U slots: slot s must hold the U columns of the pair that
  // arrives in rv after s rotations = pair (p0 +/- s) & 7.
  auto loadUrot = [&](const float* U, int col, float scl, h2* Up) {
#pragma unroll
    for (int s = 0; s < 8; ++s) {
      const int pr = rplus ? ((p0 + s) & 7) : ((p0 + 8 - s) & 7);
      const int r0 = 2 * pr, r1 = r0 + 1;
      const int rr0 = (r0 <= 10) ? r0 : 0;
      const int rr1 = (r1 <= 10) ? r1 : 0;
      float a = U[(d * NOUT + rr0) * 55 + col] * scl;
      float bb = U[(d * NOUT + rr1) * 55 + col] * scl;
      a = (r0 <= 10) ? a : 0.f;
      bb = (r1 <= 10) ? bb : 0.f;
      Up[s] = __builtin_amdgcn_cvt_pkrtz(a, bb);
    }
  };
  // Plain 6-pair form (for the y-side dots; no rotation there).
  auto loadW = [&](const float* U, int col, float scl, h2* Up) {
    float uv[12];
#pragma unroll
    for (int s = 0; s < NOUT; ++s) uv[s] = U[(d * NOUT + s) * 55 + col] * scl;
    uv[11] = 0.f;
#pragma unroll
    for (int k = 0; k < 6; ++k)
      Up[k] = __builtin_amdgcn_cvt_pkrtz(uv[2 * k], uv[2 * k + 1]);
  };

  // ---- Phase B: layer-1 scan ----
  {
    h2 UpI[8], UpF[8], UpO[8], UpA[8];
    loadUrot(U0, colI, sclS, UpI);
    loadUrot(U0, colF, sclS, UpF);
    loadUrot(U0, colO, sclS, UpO);
    loadUrot(U0, colA, sclA, UpA);
    const float WcI = W0[d * 55 + colI] * sclS;
    const float WcF = W0[d * 55 + colF] * sclS;
    const float WcO = W0[d * 55 + colO] * sclS;
    const float WcA = W0[d * 55 + colA] * sclA;
    const float bcI = b0[d * 55 + colI] * sclS;
    const float bcF = b0[d * 55 + colF] * sclS;
    const float bcO = b0[d * 55 + colO] * sclS;
    const float bcA = b0[d * 55 + colA] * sclA;

    int xo = p0pos;
    int ao = p0pos * ROW + u;  // warm never writes; in-range from main loop
    float hj = 0.f, cpr = 0.f;
    float gnI = 0.f, gnF = 0.f, gnO = 0.f, gnA = 0.f;
    const float xc = xw[xo & (WD - 1)];
    xo += xd;
    float giI = fmaf(xc, WcI, bcI);
    float giF = fmaf(xc, WcF, bcF);
    float giO = fmaf(xc, WcO, bcO);
    float giA = fmaf(xc, WcA, bcA);
    float xn = xw[xo & (WD - 1)];
    xo += xd;

#define PREP1                                                                  \
    const float xn2 = xw[xo & (WD - 1)]; /* prefetch t+2 (off-chain) */        \
    xo += xd;                                                                  \
    gnI = fmaf(xn, WcI, bcI);            /* input stage t+1 */                 \
    gnF = fmaf(xn, WcF, bcF);                                                  \
    gnO = fmaf(xn, WcO, bcO);                                                  \
    gnA = fmaf(xn, WcA, bcA);                                                  \
    xn = xn2;

    for (int t = 0; t < WARM; t += 2) {
      STEP(0, PREP1);
      giI = gnI; giF = gnF; giO = gnO; giA = gnA;
      STEP(0, PREP1);
      giI = gnI; giF = gnF; giO = gnO; giA = gnA;
    }
    // ck0's warm was wrapped garbage (uniform control flow); true initial
    // state is zero. gi pipeline holds REAL inputs for base, base+1.
    hj = ck0z ? 0.f : hj;
    cpr = ck0z ? 0.f : cpr;
    for (int t = 0; t < CHUNK; t += 2) {
      STEP(1, PREP1);
      giI = gnI; giF = gnF; giO = gnO; giA = gnA;
      STEP(1, PREP1);
      giI = gnI; giF = gnF; giO = gnO; giA = gnA;
    }
#undef PREP1
  }
  __syncthreads();

  // ---- Phase C: pack acc -> f16-pair ybf (+ zero pads); re-zero acc ----
  {
    const f2* a2 = (const f2*)acc;
    for (int i = tid; i < WD * YROW; i += NTHR) {
      const f2 v = a2[i];
      ybf[YPAD + i] = h2u(__builtin_amdgcn_cvt_pkrtz(v.x, v.y));
    }
    if (tid < YPAD) {
      ybf[tid] = 0;
      ybf[WD * YROW + YPAD + tid] = 0;
    }
  }
  __syncthreads();
  {
    f4* a4 = (f4*)acc;
    const f4 z = {0.f, 0.f, 0.f, 0.f};
    for (int i = tid; i < ACCN / 4; i += NTHR) a4[i] = z;
  }
  __syncthreads();

  // ---- Phase D: layer-2 scan ----
  {
    h2 UpI[8], UpF[8], UpO[8], UpA[8];
    h2 WpI[6], WpF[6], WpO[6], WpA[6];
    loadUrot(U1, colI, sclS, UpI);
    loadUrot(U1, colF, sclS, UpF);
    loadUrot(U1, colO, sclS, UpO);
    loadUrot(U1, colA, sclA, UpA);
    loadW(W1, colI, sclS, WpI);
    loadW(W1, colF, sclS, WpF);
    loadW(W1, colO, sclS, WpO);
    loadW(W1, colA, sclA, WpA);
    const float bcI = b1[d * 55 + colI] * sclS;
    const float bcF = b1[d * 55 + colF] * sclS;
    const float bcO = b1[d * 55 + colO] * sclS;
    const float bcA = b1[d * 55 + colA] * sclA;

    const u32x2* yv = (const u32x2*)ybf;  // row r -> yv[3r+6 .. 3r+8]
    int q = 3 * p0pos + 6;  // ck0 warm reads in-LDS/OOB garbage (benign;
                            // state rezeroed at boundary -- proven pattern)

    auto GIc = [&](const h2* Wp, float bc, u32x2 r0, u32x2 r1,
                   u32x2 r2) -> float {
      float A = dot2(u2h(r0.x), Wp[0], bc);
      A = dot2(u2h(r0.y), Wp[1], A);
      A = dot2(u2h(r1.x), Wp[2], A);
      A = dot2(u2h(r1.y), Wp[3], A);
      A = dot2(u2h(r2.x), Wp[4], A);
      A = dot2(u2h(r2.y), Wp[5], A);
      return A;
    };

    u32x2 c0 = yv[q];
    u32x2 c1 = yv[q + 1];
    u32x2 c2 = yv[q + 2];
    q += qd;
    u32x2 pr0 = yv[q];
    u32x2 pr1 = yv[q + 1];
    u32x2 pr2 = yv[q + 2];
    q += qd;

    float giI = GIc(WpI, bcI, c0, c1, c2);
    float giF = GIc(WpF, bcF, c0, c1, c2);
    float giO = GIc(WpO, bcO, c0, c1, c2);
    float giA = GIc(WpA, bcA, c0, c1, c2);

    int ao = p0pos * ROW + u;
    float hj = 0.f, cpr = 0.f;
    float gnI = 0.f, gnF = 0.f, gnO = 0.f, gnA = 0.f;

#define PREP2                                                                  \
    const u32x2 n0 = yv[q];          /* prefetch row t+2 (off-chain) */        \
    const u32x2 n1 = yv[q + 1];                                                \
    const u32x2 n2 = yv[q + 2];                                                \
    q += qd;                                                                   \
    gnI = GIc(WpI, bcI, pr0, pr1, pr2); /* input stage t+1 */                  \
    gnF = GIc(WpF, bcF, pr0, pr1, pr2);                                        \
    gnO = GIc(WpO, bcO, pr0, pr1, pr2);                                        \
    gnA = GIc(WpA, bcA, pr0, pr1, pr2);                                        \
    pr0 = n0;                                                                  \
    pr1 = n1;                                                                  \
    pr2 = n2;

    for (int t = 0; t < WARM; t += 2) {
      STEP(0, PREP2);
      giI = gnI; giF = gnF; giO = gnO; giA = gnA;
      STEP(0, PREP2);
      giI = gnI; giF = gnF; giO = gnO; giA = gnA;
    }
    hj = ck0z ? 0.f : hj;
    cpr = ck0z ? 0.f : cpr;
    for (int t = 0; t < CHUNK; t += 2) {
      STEP(1, PREP2);
      giI = gnI; giF = gnF; giO = gnO; giA = gnA;
      STEP(1, PREP2);
      giI = gnI; giF = gnF; giO = gnO; giA = gnA;
    }
#undef PREP2
  }
  __syncthreads();

  // ---- Phase E: writeout out[b][j][w] = acc[w*ROW+j] ----
  float* ob = out + (size_t)b * (NOUT * WD);
  for (int i = tid; i < NOUT * WD; i += NTHR) {
    const int jj = i >> 11;
    const int w = i & (WD - 1);
    ob[i] = acc[w * ROW + jj];
  }
}

extern "C" void kernel_launch(void* const* d_in, const int* in_sizes, int n_in,
                              void* d_out, int out_size, void* d_ws,
                              size_t ws_size, hipStream_t stream) {
  const float* x  = (const float*)d_in[0];
  const float* W0 = (const float*)d_in[1];
  const float* U0 = (const float*)d_in[2];
  const float* b0 = (const float*)d_in[3];
  const float* W1 = (const float*)d_in[4];
  const float* U1 = (const float*)d_in[5];
  const float* b1 = (const float*)d_in[6];
  float* out = (float*)d_out;

  mdlstm_fused<<<NB, NTHR, 0, stream>>>(x, W0, U0, b0, W1, U1, b1, out);
}

// Round 11
// 393.510 us; speedup vs baseline: 1.0300x; 1.0300x over previous
//
#include <hip/hip_runtime.h>
#include <hip/hip_bf16.h>

// 2-layer 4-direction MDLSTM, fused, one dispatch. B=256, Wd=2048, OUT=11.
// R18: ILP-2 CHAINS PER WAVE at NTHR=512. R15-R17 proved the NTHR=1024 path
// is dead: the backend pins VGPR=64 (8 waves/EU target) and spills ~40 regs
// of weight state (FETCH 33->75.5 MB, WRITE 22.5->106.5 MB); launch_bounds
// 2nd arg AND amdgpu_waves_per_eu are both ignored. 512-thread builds
// allocate 88-92 VGPR cleanly. So: get 4 chains/SIMD via ILP instead of TLP.
// Each wave = 4 groups x 2 chains: group g of wave wv runs direction g for
// chunks wv AND wv+8 (64 chains = 4 dirs x 16 chunks, CHUNK 128, WARM 40).
// Weights shared between the pair (same d, same unit); only ~18 regs of
// per-chain state duplicate -> ~120 VGPR. The two chains' streams are
// independent -> each wave hides its own dependence-tail latency (R14's
// 2 waves/SIMD left 200 idle cyc/slot).
// R14 carried: unit-per-lane, distribution = pure-VALU rotate-reduce
// (2 quad_perm + cvt_pkrtz put pair floor(u/2) in every lane; 7x dpp
// row_ror:2 rotates pairs through the 16-lane group; U-registers
// pre-permuted, 8 slots, pairs 6/7 zero => exact; rotation direction via
// runtime dpp probe). DS crossbar on the serial chain banned (R12/R13).
// ck0 (= chain A of wave 0) runs wrapped/OOB-in-LDS garbage warm (benign)
// + state rezero at the boundary -> uniform control flow (proven R12-R17).
// f32 LDS atomic acc; f16-pair y strip; exp2-folded activations.

#define NOUT 11
#define WD 2048
#define NB 256
#define ROW 12
#define ACCN (WD * ROW)
#define YROW 6
#define YPAD 12
#define YBFN (WD * YROW + 2 * YPAD)

#define NTHR 512
#define NCK 16      // chunks per direction (8 via chain A + 8 via chain B)
#define CHUNK 128   // WD / NCK
#define WARM 40     // uniform warm (ck0 wrapped+rezeroed); even

typedef float f2 __attribute__((ext_vector_type(2)));
typedef float f4 __attribute__((ext_vector_type(4)));
typedef unsigned int u32;
typedef u32 u32x2 __attribute__((ext_vector_type(2)));
typedef __fp16 h2 __attribute__((ext_vector_type(2)));

#define LOG2E 1.4426950408889634f

union UH { u32 u; h2 h; };
__device__ __forceinline__ u32 h2u(h2 v) { UH x; x.h = v; return x.u; }
__device__ __forceinline__ h2 u2h(u32 v) { UH x; x.u = v; return x.h; }

template <int CTRL>
__device__ __forceinline__ float dppf(float v) {
  return __int_as_float(__builtin_amdgcn_update_dpp(
      __float_as_int(v), __float_as_int(v), CTRL, 0xF, 0xF, false));
}
// row_ror:2 on a packed h2 (u32 bits); wraps within 16-lane rows.
__device__ __forceinline__ h2 rorh(h2 v) {
  return u2h((u32)__builtin_amdgcn_update_dpp(
      (int)h2u(v), (int)h2u(v), 0x122, 0xF, 0xF, false));
}
__device__ __forceinline__ float rcp_(float x) { return __builtin_amdgcn_rcpf(x); }
__device__ __forceinline__ float exp2_(float x) { return __builtin_amdgcn_exp2f(x); }
__device__ __forceinline__ float dot2(h2 a, h2 b, float c) {
  return __builtin_amdgcn_fdot2(a, b, c, false);
}

// ---- per-chain step pieces (S = chain suffix A/B) ----
#define DIST(S)                                                                \
    const float hEv##S = dppf<0xA0>(hj##S);                                    \
    const float hOd##S = dppf<0xF5>(hj##S);                                    \
    h2 rv##S = __builtin_amdgcn_cvt_pkrtz(hEv##S, hOd##S);

#define DOTS(S)                                                                \
    float gI##S = dot2(rv##S, UpI[0], giI##S);                                 \
    float gF##S = dot2(rv##S, UpF[0], giF##S);                                 \
    float gO##S = dot2(rv##S, UpO[0], giO##S);                                 \
    float gA##S = dot2(rv##S, UpA[0], giA##S);                                 \
    _Pragma("unroll")                                                          \
    for (int s = 1; s < 8; ++s) {                                              \
      rv##S = rorh(rv##S);                                                     \
      gI##S = dot2(rv##S, UpI[s], gI##S);                                      \
      gF##S = dot2(rv##S, UpF[s], gF##S);                                      \
      gO##S = dot2(rv##S, UpO[s], gO##S);                                      \
      gA##S = dot2(rv##S, UpA[s], gA##S);                                      \
    }

#define CELL(S, DOACC)                                                         \
    const float sI##S = rcp_(1.0f + exp2_(gI##S));                             \
    const float sF##S = rcp_(1.0f + exp2_(gF##S));                             \
    const float sO##S = rcp_(1.0f + exp2_(gO##S));                             \
    const float sA##S = rcp_(1.0f + exp2_(gA##S));                             \
    const float taS##S = fmaf(-4.0f * LOG2E, sA##S, 2.0f * LOG2E);             \
    cpr##S = fmaf(sF##S, cpr##S, sI##S * taS##S);                              \
    const float r2t##S = rcp_(1.0f + exp2_(cpr##S));                           \
    const float sO2##S = sO##S + sO##S;                                        \
    hj##S = fmaf(sO2##S, r2t##S, -sO##S);                                      \
    if (DOACC && wr) atomicAdd(&acc[ao##S], hj##S);                            \
    ao##S += ad;

#define COPY(S)                                                                \
    giI##S = gnI##S; giF##S = gnF##S; giO##S = gnO##S; giA##S = gnA##S;

#define L1PREP(S)                                                              \
    const float xn2##S = xw[xo##S & (WD - 1)];                                 \
    xo##S += xd;                                                               \
    gnI##S = fmaf(xn##S, WcI, bcI);                                            \
    gnF##S = fmaf(xn##S, WcF, bcF);                                            \
    gnO##S = fmaf(xn##S, WcO, bcO);                                            \
    gnA##S = fmaf(xn##S, WcA, bcA);                                            \
    xn##S = xn2##S;

#define L2PREP(S)                                                              \
    const u32x2 n0##S = yv[q##S];                                              \
    const u32x2 n1##S = yv[q##S + 1];                                          \
    const u32x2 n2##S = yv[q##S + 2];                                          \
    q##S += qd;                                                                \
    gnI##S = GIc(WpI, bcI, pr0##S, pr1##S, pr2##S);                            \
    gnF##S = GIc(WpF, bcF, pr0##S, pr1##S, pr2##S);                            \
    gnO##S = GIc(WpO, bcO, pr0##S, pr1##S, pr2##S);                            \
    gnA##S = GIc(WpA, bcA, pr0##S, pr1##S, pr2##S);                            \
    pr0##S = n0##S; pr1##S = n1##S; pr2##S = n2##S;

#define L1STEP(DOACC)                                                          \
    { DIST(A) DIST(B) L1PREP(A) L1PREP(B) DOTS(A) DOTS(B)                      \
      CELL(A, DOACC) CELL(B, DOACC) COPY(A) COPY(B) }

#define L2STEP(DOACC)                                                          \
    { DIST(A) DIST(B) L2PREP(A) L2PREP(B) DOTS(A) DOTS(B)                      \
      CELL(A, DOACC) CELL(B, DOACC) COPY(A) COPY(B) }

__global__ __launch_bounds__(NTHR, 1) void mdlstm_fused(
    const float* __restrict__ x, const float* __restrict__ W0,
    const float* __restrict__ U0, const float* __restrict__ b0,
    const float* __restrict__ W1, const float* __restrict__ U1,
    const float* __restrict__ b1, float* __restrict__ out) {
  __shared__ __align__(16) float acc[ACCN];  // 96 KB
  __shared__ __align__(16) u32 ybf[YBFN];    // 48.1 KB (xw f32 | y f16-pairs)

  const int tid = threadIdx.x;
  const int b = blockIdx.x;
  float* xw = (float*)ybf;

  // ---- Phase A: height-sum x -> xw; zero acc ----
  {
    const f4* xb4 = (const f4*)(x + (size_t)b * 32 * WD);
    f4* xw4 = (f4*)xw;
    for (int w = tid; w < WD / 4; w += NTHR) {
      f4 s = xb4[w];
#pragma unroll
      for (int h = 1; h < 32; ++h) s += xb4[h * (WD / 4) + w];
      xw4[w] = s;
    }
    f4* a4 = (f4*)acc;
    const f4 z = {0.f, 0.f, 0.f, 0.f};
    for (int i = tid; i < ACCN / 4; i += NTHR) a4[i] = z;
  }
  __syncthreads();

  const int lane = tid & 63;
  const int wv = tid >> 6;          // 0..7
  const int grp = lane >> 4;        // group 0..3
  const int u = lane & 15;          // unit 0..15 (11..15 dummy)
  const int d = grp;                // direction (one per group)
  const int ckA = wv;               // chain A chunk 0..7
  const int ckB = wv + 8;           // chain B chunk 8..15
  const bool fwd = ((d & 1) == 0);
  const bool real = (u <= 10);
  const bool wr = real;
  const bool ck0zA = (wv == 0);     // chain A of wave 0 = the 4 ck0 chains
  // gate cols: i:0-10 f:11-21 o:33-43 a:44-54; dummy -> col 54, scl 0
  const int colI = real ? u : 54;
  const int colF = real ? (11 + u) : 54;
  const int colO = real ? (33 + u) : 54;
  const int colA = real ? (44 + u) : 54;
  const float sclS = real ? -LOG2E : 0.f;          // i, f, o
  const float sclA = real ? (-2.f * LOG2E) : 0.f;  // a

  // Rotation-direction probe: does row_ror:2 read lane i+2 or i-2?
  const int li = lane & 15;
  const int pv =
      __builtin_amdgcn_update_dpp(0, li, 0x122, 0xF, 0xF, false);
  const bool rplus = (pv == ((li + 2) & 15));
  const int p0 = li >> 1;  // own pair index 0..7

  const int baseA = ckA * CHUNK;
  const int baseB = ckB * CHUNK;
  const int p0A = fwd ? (baseA - WARM) : (WD - 1 - baseA + WARM);
  const int p0B = fwd ? (baseB - WARM) : (WD - 1 - baseB + WARM);
  const int xd = fwd ? 1 : -1;
  const int ad = fwd ? ROW : -ROW;
  const int qd = fwd ? 3 : -3;

  // Rotated U slots: slot s must hold the U columns of the pair that
  // arrives in rv after s rotations = pair (p0 +/- s) & 7.
  auto loadUrot = [&](const float* U, int col, float scl, h2* Up) {
#pragma unroll
    for (int s = 0; s < 8; ++s) {
      const int pr = rplus ? ((p0 + s) & 7) : ((p0 + 8 - s) & 7);
      const int r0 = 2 * pr, r1 = r0 + 1;
      const int rr0 = (r0 <= 10) ? r0 : 0;
      const int rr1 = (r1 <= 10) ? r1 : 0;
      float a = U[(d * NOUT + rr0) * 55 + col] * scl;
      float bb = U[(d * NOUT + rr1) * 55 + col] * scl;
      a = (r0 <= 10) ? a : 0.f;
      bb = (r1 <= 10) ? bb : 0.f;
      Up[s] = __builtin_amdgcn_cvt_pkrtz(a, bb);
    }
  };
  // Plain 6-pair form (for the y-side dots; no rotation there).
  auto loadW = [&](const float* U, int col, float scl, h2* Up) {
    float uv[12];
#pragma unroll
    for (int s = 0; s < NOUT; ++s) uv[s] = U[(d * NOUT + s) * 55 + col] * scl;
    uv[11] = 0.f;
#pragma unroll
    for (int k = 0; k < 6; ++k)
      Up[k] = __builtin_amdgcn_cvt_pkrtz(uv[2 * k], uv[2 * k + 1]);
  };

  // ---- Phase B: layer-1 scan (two chains per wave) ----
  {
    h2 UpI[8], UpF[8], UpO[8], UpA[8];
    loadUrot(U0, colI, sclS, UpI);
    loadUrot(U0, colF, sclS, UpF);
    loadUrot(U0, colO, sclS, UpO);
    loadUrot(U0, colA, sclA, UpA);
    const float WcI = W0[d * 55 + colI] * sclS;
    const float WcF = W0[d * 55 + colF] * sclS;
    const float WcO = W0[d * 55 + colO] * sclS;
    const float WcA = W0[d * 55 + colA] * sclA;
    const float bcI = b0[d * 55 + colI] * sclS;
    const float bcF = b0[d * 55 + colF] * sclS;
    const float bcO = b0[d * 55 + colO] * sclS;
    const float bcA = b0[d * 55 + colA] * sclA;

    int xoA = p0A, xoB = p0B;
    int aoA = p0A * ROW + u, aoB = p0B * ROW + u;  // warm never writes
    float hjA = 0.f, cprA = 0.f, hjB = 0.f, cprB = 0.f;
    float gnIA = 0.f, gnFA = 0.f, gnOA = 0.f, gnAA = 0.f;
    float gnIB = 0.f, gnFB = 0.f, gnOB = 0.f, gnAB = 0.f;
    const float xcA = xw[xoA & (WD - 1)];
    const float xcB = xw[xoB & (WD - 1)];
    xoA += xd; xoB += xd;
    float giIA = fmaf(xcA, WcI, bcI), giFA = fmaf(xcA, WcF, bcF);
    float giOA = fmaf(xcA, WcO, bcO), giAA = fmaf(xcA, WcA, bcA);
    float giIB = fmaf(xcB, WcI, bcI), giFB = fmaf(xcB, WcF, bcF);
    float giOB = fmaf(xcB, WcO, bcO), giAB = fmaf(xcB, WcA, bcA);
    float xnA = xw[xoA & (WD - 1)];
    float xnB = xw[xoB & (WD - 1)];
    xoA += xd; xoB += xd;

    for (int t = 0; t < WARM; t += 2) {
      L1STEP(0);
      L1STEP(0);
    }
    // Chain A of wave 0 ran a wrapped garbage warm (uniform control flow);
    // its true initial state is exactly zero. gi pipelines hold REAL inputs.
    hjA = ck0zA ? 0.f : hjA;
    cprA = ck0zA ? 0.f : cprA;
    for (int t = 0; t < CHUNK; t += 2) {
      L1STEP(1);
      L1STEP(1);
    }
  }
  __syncthreads();

  // ---- Phase C: pack acc -> f16-pair ybf (+ zero pads); re-zero acc ----
  {
    const f2* a2 = (const f2*)acc;
    for (int i = tid; i < WD * YROW; i += NTHR) {
      const f2 v = a2[i];
      ybf[YPAD + i] = h2u(__builtin_amdgcn_cvt_pkrtz(v.x, v.y));
    }
    if (tid < YPAD) {
      ybf[tid] = 0;
      ybf[WD * YROW + YPAD + tid] = 0;
    }
  }
  __syncthreads();
  {
    f4* a4 = (f4*)acc;
    const f4 z = {0.f, 0.f, 0.f, 0.f};
    for (int i = tid; i < ACCN / 4; i += NTHR) a4[i] = z;
  }
  __syncthreads();

  // ---- Phase D: layer-2 scan (two chains per wave) ----
  {
    h2 UpI[8], UpF[8], UpO[8], UpA[8];
    h2 WpI[6], WpF[6], WpO[6], WpA[6];
    loadUrot(U1, colI, sclS, UpI);
    loadUrot(U1, colF, sclS, UpF);
    loadUrot(U1, colO, sclS, UpO);
    loadUrot(U1, colA, sclA, UpA);
    loadW(W1, colI, sclS, WpI);
    loadW(W1, colF, sclS, WpF);
    loadW(W1, colO, sclS, WpO);
    loadW(W1, colA, sclA, WpA);
    const float bcI = b1[d * 55 + colI] * sclS;
    const float bcF = b1[d * 55 + colF] * sclS;
    const float bcO = b1[d * 55 + colO] * sclS;
    const float bcA = b1[d * 55 + colA] * sclA;

    const u32x2* yv = (const u32x2*)ybf;  // row r -> yv[3r+6 .. 3r+8]
    int qA = 3 * p0A + 6;  // ck0 warm reads in-LDS/OOB garbage (benign;
    int qB = 3 * p0B + 6;  // state rezeroed at boundary -- proven pattern)

    auto GIc = [&](const h2* Wp, float bc, u32x2 r0, u32x2 r1,
                   u32x2 r2) -> float {
      float A = dot2(u2h(r0.x), Wp[0], bc);
      A = dot2(u2h(r0.y), Wp[1], A);
      A = dot2(u2h(r1.x), Wp[2], A);
      A = dot2(u2h(r1.y), Wp[3], A);
      A = dot2(u2h(r2.x), Wp[4], A);
      A = dot2(u2h(r2.y), Wp[5], A);
      return A;
    };

    u32x2 c0A = yv[qA], c1A = yv[qA + 1], c2A = yv[qA + 2];
    u32x2 c0B = yv[qB], c1B = yv[qB + 1], c2B = yv[qB + 2];
    qA += qd; qB += qd;
    u32x2 pr0A = yv[qA], pr1A = yv[qA + 1], pr2A = yv[qA + 2];
    u32x2 pr0B = yv[qB], pr1B = yv[qB + 1], pr2B = yv[qB + 2];
    qA += qd; qB += qd;

    float giIA = GIc(WpI, bcI, c0A, c1A, c2A);
    float giFA = GIc(WpF, bcF, c0A, c1A, c2A);
    float giOA = GIc(WpO, bcO, c0A, c1A, c2A);
    float giAA = GIc(WpA, bcA, c0A, c1A, c2A);
    float giIB = GIc(WpI, bcI, c0B, c1B, c2B);
    float giFB = GIc(WpF, bcF, c0B, c1B, c2B);
    float giOB = GIc(WpO, bcO, c0B, c1B, c2B);
    float giAB = GIc(WpA, bcA, c0B, c1B, c2B);

    int aoA = p0A * ROW + u, aoB = p0B * ROW + u;
    float hjA = 0.f, cprA = 0.f, hjB = 0.f, cprB = 0.f;
    float gnIA = 0.f, gnFA = 0.f, gnOA = 0.f, gnAA = 0.f;
    float gnIB = 0.f, gnFB = 0.f, gnOB = 0.f, gnAB = 0.f;

    for (int t = 0; t < WARM; t += 2) {
      L2STEP(0);
      L2STEP(0);
    }
    hjA = ck0zA ? 0.f : hjA;
    cprA = ck0zA ? 0.f : cprA;
    for (int t = 0; t < CHUNK; t += 2) {
      L2STEP(1);
      L2STEP(1);
    }
  }
  __syncthreads();

  // ---- Phase E: writeout out[b][j][w] = acc[w*ROW+j] ----
  float* ob = out + (size_t)b * (NOUT * WD);
  for (int i = tid; i < NOUT * WD; i += NTHR) {
    const int jj = i >> 11;
    const int w = i & (WD - 1);
    ob[i] = acc[w * ROW + jj];
  }
}

extern "C" void kernel_launch(void* const* d_in, const int* in_sizes, int n_in,
                              void* d_out, int out_size, void* d_ws,
                              size_t ws_size, hipStream_t stream) {
  const float* x  = (const float*)d_in[0];
  const float* W0 = (const float*)d_in[1];
  const float* U0 = (const float*)d_in[2];
  const float* b0 = (const float*)d_in[3];
  const float* W1 = (const float*)d_in[4];
  const float* U1 = (const float*)d_in[5];
  const float* b1 = (const float*)d_in[6];
  float* out = (float*)d_out;

  mdlstm_fused<<<NB, NTHR, 0, stream>>>(x, W0, U0, b0, W1, U1, b1, out);
}